// Round 6
// baseline (814.468 us; speedup 1.0000x reference)
//
#include <hip/hip_runtime.h>
#include <stdint.h>

#define CDIM   4096
#define S_N    3355443
#define R_N    1048576
#define N1     (S_N + R_N)                 // 4404019 contributions
#define TILE   4096
#define NTILES 1076                        // ceil(N1/TILE)
#define NPAD   (NTILES * TILE)             // 4407296
#define NT2    320                         // survivor tiles (1.31M slots)
#define SPAD   (NT2 * TILE)                // 1310720
#define PAD_KEY 0xFFFFFFu
#define PAD_VAL 0xFFFFFFFFu                // impossible raw value bits
#define PADREC  ((((uint64_t)PAD_KEY) << 32) | (uint64_t)PAD_VAL)

// Exclusive block-wide scan over 256 threads (4 waves). Contains syncthreads.
static __device__ __forceinline__ unsigned blockScanExcl(unsigned v, unsigned t,
                                                         unsigned* lw, unsigned* tot){
  unsigned lane = t & 63u, w = t >> 6;
  unsigned x = v;
  #pragma unroll
  for (int off = 1; off < 64; off <<= 1){
    unsigned y = __shfl_up(x, off, 64);
    if (lane >= (unsigned)off) x += y;
  }
  if (lane == 63u) lw[w] = x;
  __syncthreads();
  unsigned woff = 0;
  for (unsigned i = 0; i < w; i++) woff += lw[i];
  *tot = lw[0] + lw[1] + lw[2] + lw[3];
  __syncthreads();
  return x + woff - v;
}

// Completion-counter plumbing (rocPRIM-style). Release-add after block work;
// acquire-spin / last-finisher pick up cross-block results.
static __device__ __forceinline__ void block_signal(unsigned* cnt, unsigned* ord_sh){
  __syncthreads();
  if (threadIdx.x == 0)
    *ord_sh = __hip_atomic_fetch_add(cnt, 1u, __ATOMIC_ACQ_REL, __HIP_MEMORY_SCOPE_AGENT);
  __syncthreads();
}
static __device__ __forceinline__ void spin_until(unsigned* cnt, unsigned total){
  if (threadIdx.x == 0){
    while (__hip_atomic_load(cnt, __ATOMIC_ACQUIRE, __HIP_MEMORY_SCOPE_AGENT) < total)
      __builtin_amdgcn_s_sleep(1);
  }
  __syncthreads();
}
// Row scan for fused hist+scanrows: block d scans gh[d][*] -> prefixes + dtot.
static __device__ __forceinline__ void scan_row(unsigned* gh, unsigned* dtot, unsigned nt){
  __shared__ unsigned lw_sr[4];
  unsigned d = blockIdx.x, t = threadIdx.x;
  unsigned carry = 0;
  for (unsigned base = 0; base < nt; base += 256){
    unsigned i = base + t;
    unsigned v = (i < nt) ? gh[d*nt + i] : 0u;
    unsigned tot; unsigned e = blockScanExcl(v, t, lw_sr, &tot);
    if (i < nt) gh[d*nt + i] = e + carry;
    carry += tot;
  }
  if (t == 0) dtot[d] = carry;
}

__global__ __launch_bounds__(256) void k_zero(unsigned* __restrict__ p, unsigned n){
  unsigned i = blockIdx.x * 256u + threadIdx.x;
  if (i < n) p[i] = 0u;
}

// Build + fused pass-1 (low key byte) per-tile hist + fused row scan.
__global__ __launch_bounds__(256, 6) void k_build_hs(const int* __restrict__ sidx,
    const int* __restrict__ ridx, const float* __restrict__ rval,
    const float* __restrict__ grad, uint64_t* __restrict__ A,
    unsigned* __restrict__ gh, unsigned* __restrict__ dtot, unsigned* __restrict__ cnt){
  __shared__ unsigned h[256];
  __shared__ unsigned ord;
  unsigned t = threadIdx.x;
  h[t] = 0; __syncthreads();
  unsigned base = blockIdx.x * (unsigned)TILE;
  #pragma unroll
  for (int r = 0; r < 16; r++){
    unsigned i = base + (unsigned)r*256u + t;
    uint32_t key, vb;
    if (i < S_N){
      key = (uint32_t)sidx[i];
      vb  = __float_as_uint(fabsf(grad[i]));
    } else if (i < N1){
      unsigned j = i - S_N;
      key = (uint32_t)(ridx[2u*j] * CDIM + ridx[2u*j + 1u]);
      const float ADJF = (float)(1.0 - (3355443.0 / 16777216.0) * (1.0 - 0.95));
      vb = __float_as_uint(ADJF * rval[j]);
    } else { key = PAD_KEY; vb = PAD_VAL; }
    A[i] = ((uint64_t)key << 32) | (uint64_t)vb;
    atomicAdd(&h[key & 0xFFu], 1u);
  }
  __syncthreads();
  gh[t*NTILES + blockIdx.x] = h[t];
  block_signal(cnt, &ord);
  if (blockIdx.x < 256){
    spin_until(cnt, NTILES);
    scan_row(gh, dtot, NTILES);
  }
}

// Generic per-tile hist + fused row scan (all co-resident: grid <= 1536).
__global__ __launch_bounds__(256, 6) void k_hist_s(const uint64_t* __restrict__ in,
    unsigned shift, unsigned* __restrict__ gh, unsigned* __restrict__ dtot,
    unsigned* __restrict__ cnt, unsigned nt){
  __shared__ unsigned h[256];
  __shared__ unsigned ord;
  unsigned t = threadIdx.x;
  h[t] = 0; __syncthreads();
  size_t base = (size_t)blockIdx.x * TILE;
  #pragma unroll
  for (int r = 0; r < 16; r++){
    uint64_t e = in[base + (size_t)r*256 + t];
    atomicAdd(&h[(unsigned)((e >> shift) & 0xFF)], 1u);
  }
  __syncthreads();
  gh[t*nt + blockIdx.x] = h[t];
  block_signal(cnt, &ord);
  if (blockIdx.x < 256){
    spin_until(cnt, nt);
    scan_row(gh, dtot, nt);
  }
}

// ---- LDS-staged stable radix scatter (round-2 proven) --------------------
template <bool FINAL>
__device__ __forceinline__ void scatter_body(const uint64_t* __restrict__ in,
                                             uint64_t* __restrict__ out,
                                             float* __restrict__ fout,
                                             unsigned shift,
                                             const unsigned* __restrict__ gh,
                                             const unsigned* __restrict__ dtot,
                                             unsigned nt){
  __shared__ unsigned wrun[4*256];
  __shared__ unsigned gput[256];
  __shared__ unsigned lw[4];
  __shared__ uint64_t stage[TILE];       // 32 KB
  unsigned t = threadIdx.x, lane = t & 63u, w = t >> 6;
  wrun[t] = 0; wrun[256+t] = 0; wrun[512+t] = 0; wrun[768+t] = 0;
  __syncthreads();
  uint64_t ltm = (lane == 0) ? 0ull : (~0ull >> (64u - lane));
  uint64_t elems[16]; unsigned rnk[16]; unsigned dg[16];
  size_t base = (size_t)blockIdx.x * TILE + (size_t)w * 1024;
  #pragma unroll
  for (int r = 0; r < 16; r++){
    uint64_t e = in[base + (size_t)r*64 + lane];
    elems[r] = e;
    unsigned d = (unsigned)((e >> shift) & 0xFF);
    uint64_t m = ~0ull;
    #pragma unroll
    for (int b = 0; b < 8; b++){
      uint64_t bb = __ballot((d >> b) & 1u);
      m &= ((d >> b) & 1u) ? bb : ~bb;
    }
    unsigned rr   = (unsigned)__popcll(m & ltm);
    unsigned prev = wrun[w*256 + d];
    __builtin_amdgcn_wave_barrier();
    if (rr == 0) wrun[w*256 + d] = prev + (unsigned)__popcll(m);
    __builtin_amdgcn_wave_barrier();
    rnk[r] = prev + rr;
    dg[r]  = d;
  }
  __syncthreads();
  {
    unsigned d = t;
    unsigned c0 = wrun[d], c1 = wrun[256+d], c2 = wrun[512+d], c3 = wrun[768+d];
    unsigned cnt_ = c0 + c1 + c2 + c3;
    unsigned tot, tot2;
    unsigned ldig  = blockScanExcl(cnt_, t, lw, &tot);
    unsigned dbase = blockScanExcl(dtot[d], t, lw, &tot2);
    gput[d] = dbase + gh[d * nt + blockIdx.x] - ldig;
    wrun[d]       = ldig;
    wrun[256 + d] = ldig + c0;
    wrun[512 + d] = ldig + c0 + c1;
    wrun[768 + d] = ldig + c0 + c1 + c2;
  }
  __syncthreads();
  #pragma unroll
  for (int r = 0; r < 16; r++)
    stage[ wrun[w*256 + dg[r]] + rnk[r] ] = elems[r];
  __syncthreads();
  #pragma unroll
  for (int r = 0; r < 16; r++){
    unsigned j = (unsigned)r * 256u + t;
    uint64_t e = stage[j];
    unsigned d = (unsigned)((e >> shift) & 0xFF);
    unsigned dest = gput[d] + j;
    if (FINAL){
      if (dest < R_N){
        uint32_t key = (uint32_t)(e >> 32);
        fout[2u*dest]        = (float)(key >> 12);
        fout[2u*dest + 1u]   = (float)(key & 4095u);
        fout[2u*R_N + dest]  = __uint_as_float(~(uint32_t)e);
      }
    } else {
      out[dest] = e;
    }
  }
}

__global__ __launch_bounds__(256) void k_scatter(const uint64_t* __restrict__ in,
    uint64_t* __restrict__ out, unsigned shift, const unsigned* __restrict__ gh,
    const unsigned* __restrict__ dtot, unsigned nt){
  scatter_body<false>(in, out, nullptr, shift, gh, dtot, nt);
}
__global__ __launch_bounds__(256) void k_scatter_out(const uint64_t* __restrict__ in,
    float* __restrict__ fout, unsigned shift, const unsigned* __restrict__ gh,
    const unsigned* __restrict__ dtot, unsigned nt){
  scatter_body<true>(in, nullptr, fout, shift, gh, dtot, nt);
}

// In-order segmented sum, SPARSE output (candidate at head position, PADREC
// elsewhere -> key-ascending by construction, no headcount/scan needed).
// Fused: per-tile 12-bit sortkey-prefix histogram (u16 row) for radix-select.
__global__ __launch_bounds__(256) void k_segsum12(const uint64_t* __restrict__ in,
    uint64_t* __restrict__ out, unsigned short* __restrict__ g12){
  __shared__ unsigned h12[4096];         // 16 KB
  unsigned t = threadIdx.x;
  for (unsigned j = t; j < 4096u; j += 256u) h12[j] = 0;
  __syncthreads();
  size_t base = (size_t)blockIdx.x * TILE;
  for (int r = 0; r < 16; r++){
    size_t p = base + (size_t)r*256 + t;
    uint64_t e0 = in[p];
    uint32_t k = (uint32_t)(e0 >> 32);
    uint32_t vb0 = (uint32_t)e0;
    bool head = ((p == 0) || ((uint32_t)(in[p-1] >> 32) != k)) && (vb0 != PAD_VAL);
    uint64_t rec = PADREC;
    if (head){
      float s = __uint_as_float(vb0);
      size_t q = p + 1;
      while (q < NPAD){
        uint64_t e = in[q];
        if ((uint32_t)(e >> 32) != k) break;
        uint32_t vb = (uint32_t)e;
        if (vb == PAD_VAL) break;
        s += __uint_as_float(vb);       // fp32, original order == segment_sum
        q++;
      }
      uint32_t sk = ~__float_as_uint(s);
      rec = ((uint64_t)k << 32) | (uint64_t)sk;
      atomicAdd(&h12[sk >> 20], 1u);
    }
    out[p] = rec;
  }
  __syncthreads();
  unsigned short* row = g12 + (size_t)blockIdx.x * 4096;
  for (unsigned j = t; j < 4096u; j += 256u) row[j] = (unsigned short)h12[j];
}

// Fold g12 rows (16 blocks x ~68 tiles, coalesced) -> partial sums; the LAST
// block also sums partials, scans 4096 bins, picks thr12 (first bin with
// cumulative >= R). No spin needed (dynamic single finisher).
__global__ __launch_bounds__(256) void k_fold12p(const unsigned short* __restrict__ g12,
    unsigned* __restrict__ partial, unsigned* __restrict__ sel, unsigned* __restrict__ cnt){
  __shared__ unsigned acc[4096];
  __shared__ unsigned ord;
  __shared__ unsigned lw[4];
  __shared__ unsigned fl[4];
  __shared__ unsigned thr_sh;
  unsigned t = threadIdx.x, lane = t & 63u, w = t >> 6;
  for (unsigned j = t; j < 4096u; j += 256u) acc[j] = 0;
  __syncthreads();
  unsigned t0 = blockIdx.x * 68u, t1 = min(t0 + 68u, (unsigned)NTILES);
  for (unsigned tile = t0; tile < t1; tile++){
    const unsigned short* row = g12 + (size_t)tile * 4096;
    for (unsigned j = t; j < 4096u; j += 256u) acc[j] += row[j];
  }
  __syncthreads();
  for (unsigned j = t; j < 4096u; j += 256u) partial[blockIdx.x*4096u + j] = acc[j];
  block_signal(cnt, &ord);
  if (ord == 15u){                       // last of 16: finish
    for (unsigned j = t; j < 4096u; j += 256u){
      unsigned s = 0;
      for (unsigned i = 0; i < 16u; i++) s += partial[i*4096u + j];
      acc[j] = s;
    }
    if (t == 0) thr_sh = 0xFFFFFFFFu;
    __syncthreads();
    unsigned carry = 0;
    for (unsigned c = 0; c < 16u; c++){
      unsigned v = acc[c*256u + t];
      unsigned tot; unsigned e = blockScanExcl(v, t, lw, &tot);
      bool f = (carry + e + v >= (unsigned)R_N);
      uint64_t m = __ballot(f);
      if (lane == 0)
        fl[w] = m ? (w*64u + (unsigned)__ffsll((unsigned long long)m) - 1u) : 0xFFFFFFFFu;
      __syncthreads();
      if (t == 0 && thr_sh == 0xFFFFFFFFu){
        unsigned bb = min(min(fl[0], fl[1]), min(fl[2], fl[3]));
        if (bb != 0xFFFFFFFFu) thr_sh = c*256u + bb;
      }
      __syncthreads();
      carry += tot;
    }
    if (t == 0) sel[0] = (thr_sh == 0xFFFFFFFFu) ? 4095u : thr_sh;
  }
}

// Per-tile survivor count from g12 (no re-read of A0); last block scans the
// 1076 counts in LDS -> exclusive bases (in place) + mtot.
__global__ __launch_bounds__(256) void k_tilecnt_s(const unsigned short* __restrict__ g12,
    const unsigned* __restrict__ sel, unsigned* __restrict__ ccnt,
    unsigned* __restrict__ mtot, unsigned* __restrict__ cnt){
  __shared__ unsigned lw[4];
  __shared__ unsigned ord;
  __shared__ unsigned thr_sh;
  __shared__ unsigned buf[NTILES];       // 4.3 KB
  unsigned t = threadIdx.x;
  if (t == 0) thr_sh = sel[0];
  __syncthreads();
  unsigned thr = thr_sh;
  const unsigned short* row = g12 + (size_t)blockIdx.x * 4096;
  unsigned s = 0;
  for (unsigned j = t; j <= thr; j += 256u) s += row[j];
  unsigned tot; blockScanExcl(s, t, lw, &tot);
  if (t == 0) ccnt[blockIdx.x] = tot;
  block_signal(cnt, &ord);
  if (ord == NTILES - 1u){
    for (unsigned i = t; i < NTILES; i += 256u) buf[i] = ccnt[i];
    __syncthreads();
    unsigned carry = 0;
    for (unsigned base = 0; base < NTILES; base += 256u){
      unsigned i = base + t;
      unsigned v = (i < NTILES) ? buf[i] : 0u;
      unsigned tt; unsigned e = blockScanExcl(v, t, lw, &tt);
      if (i < NTILES) ccnt[i] = carry + e;
      carry += tt;
    }
    if (t == 0) mtot[0] = carry;
  }
}

// Stable per-tile compaction of survivors (sk12 <= thr) A0 -> A1[0,M),
// fused PAD tail fill of [M, SPAD).
__global__ __launch_bounds__(256) void k_compact(const uint64_t* __restrict__ A0,
    uint64_t* __restrict__ A1, const unsigned* __restrict__ cbase,
    const unsigned* __restrict__ mtot, const unsigned* __restrict__ sel){
  __shared__ unsigned wsum[4];
  __shared__ unsigned thr_sh;
  unsigned t = threadIdx.x, lane = t & 63u, w = t >> 6;
  if (t == 0) thr_sh = sel[0];
  __syncthreads();
  unsigned thr = thr_sh;
  uint64_t ltm = (lane == 0) ? 0ull : (~0ull >> (64u - lane));
  uint64_t e[16]; unsigned rnk[16]; unsigned qb = 0;
  size_t base = (size_t)blockIdx.x * TILE + (size_t)w * 1024;
  unsigned wcount = 0;
  #pragma unroll
  for (int r = 0; r < 16; r++){
    uint64_t x = A0[base + (size_t)r*64 + lane];
    e[r] = x;
    bool q = ((((uint32_t)x) >> 20) <= thr);
    uint64_t m = __ballot(q);
    rnk[r] = wcount + (unsigned)__popcll(m & ltm);
    wcount += (unsigned)__popcll(m);
    qb |= (q ? 1u : 0u) << r;
  }
  if (lane == 0) wsum[w] = wcount;
  __syncthreads();
  unsigned woff = 0;
  for (unsigned i = 0; i < w; i++) woff += wsum[i];
  unsigned b0 = cbase[blockIdx.x] + woff;
  #pragma unroll
  for (int r = 0; r < 16; r++)
    if ((qb >> r) & 1u){
      unsigned dest = b0 + rnk[r];
      if (dest < (unsigned)SPAD) A1[dest] = e[r];
    }
  unsigned M = mtot[0];
  for (size_t p = (size_t)M + blockIdx.x*256u + t; p < (size_t)SPAD; p += (size_t)NTILES*256u)
    A1[p] = PADREC;
}

extern "C" void kernel_launch(void* const* d_in, const int* in_sizes, int n_in,
                              void* d_out, int out_size, void* d_ws, size_t ws_size,
                              hipStream_t stream) {
  const int*   sidx = (const int*)d_in[0];
  const int*   ridx = (const int*)d_in[1];
  const float* rval = (const float*)d_in[2];
  const float* grad = (const float*)d_in[3];
  float* out = (float*)d_out;

  uint64_t* A0      = (uint64_t*)d_ws;                    // 35.3 MB
  uint64_t* A1      = A0 + NPAD;                          // 35.3 MB
  unsigned* gh      = (unsigned*)(A1 + NPAD);             // 1.1 MB
  unsigned* dtot    = gh + 256 * NTILES;
  unsigned* partial = dtot + 256;                         // 256 KB
  unsigned* ccnt    = partial + 16*4096;                  // 4.3 KB
  unsigned* mtot    = ccnt + NTILES;
  unsigned* sel     = mtot + 1;
  unsigned* cnts    = sel + 4;                            // 16 counters
  unsigned short* g12 = (unsigned short*)(cnts + 16);     // 8.8 MB

  k_zero<<<1, 256, 0, stream>>>(sel, 20);                 // sel[4] + cnts[16]

  // Build + fused pass-1 hist+scan; stable key sort 3 x 8-bit. A0->A1->A0->A1.
  k_build_hs<<<NTILES, 256, 0, stream>>>(sidx, ridx, rval, grad, A0, gh, dtot, cnts + 0);
  k_scatter <<<NTILES, 256, 0, stream>>>(A0, A1, 32, gh, dtot, NTILES);
  k_hist_s  <<<NTILES, 256, 0, stream>>>(A1, 40, gh, dtot, cnts + 1, NTILES);
  k_scatter <<<NTILES, 256, 0, stream>>>(A1, A0, 40, gh, dtot, NTILES);
  k_hist_s  <<<NTILES, 256, 0, stream>>>(A0, 48, gh, dtot, cnts + 2, NTILES);
  k_scatter <<<NTILES, 256, 0, stream>>>(A0, A1, 48, gh, dtot, NTILES);

  // Coalesce sparse (A1 -> A0) + per-tile 12-bit select hist; pick threshold;
  // per-tile survivor counts + bases; stable compact + tail fill (A0 -> A1).
  k_segsum12 <<<NTILES, 256, 0, stream>>>(A1, A0, g12);
  k_fold12p  <<<16,     256, 0, stream>>>(g12, partial, sel, cnts + 3);
  k_tilecnt_s<<<NTILES, 256, 0, stream>>>(g12, sel, ccnt, mtot, cnts + 4);
  k_compact  <<<NTILES, 256, 0, stream>>>(A0, A1, ccnt, mtot, sel);

  // Stable value sort on survivors: 4 x 8-bit, final fused with output.
  // A1->A0->A1->A0->out.
  k_hist_s     <<<NT2, 256, 0, stream>>>(A1, 0, gh, dtot, cnts + 5, NT2);
  k_scatter    <<<NT2, 256, 0, stream>>>(A1, A0, 0, gh, dtot, NT2);
  k_hist_s     <<<NT2, 256, 0, stream>>>(A0, 8, gh, dtot, cnts + 6, NT2);
  k_scatter    <<<NT2, 256, 0, stream>>>(A0, A1, 8, gh, dtot, NT2);
  k_hist_s     <<<NT2, 256, 0, stream>>>(A1, 16, gh, dtot, cnts + 7, NT2);
  k_scatter    <<<NT2, 256, 0, stream>>>(A1, A0, 16, gh, dtot, NT2);
  k_hist_s     <<<NT2, 256, 0, stream>>>(A0, 24, gh, dtot, cnts + 8, NT2);
  k_scatter_out<<<NT2, 256, 0, stream>>>(A0, out, 24, gh, dtot, NT2);
}

// Round 7
// 437.395 us; speedup vs baseline: 1.8621x; 1.8621x over previous
//
#include <hip/hip_runtime.h>
#include <stdint.h>

#define CDIM   4096
#define S_N    3355443
#define R_N    1048576
#define N1     (S_N + R_N)                 // 4404019 contributions
#define TILE   4096
#define NTILES 1076                        // ceil(N1/TILE)
#define NPAD   (NTILES * TILE)             // 4407296
#define NT2    320                         // survivor tiles (1.31M slots)
#define SPAD   (NT2 * TILE)                // 1310720
#define PAD_KEY 0xFFFFFFu
#define PAD_VAL 0xFFFFFFFFu                // impossible raw value bits
#define PADREC  ((((uint64_t)PAD_KEY) << 32) | (uint64_t)PAD_VAL)

// Exclusive block-wide scan over 256 threads (4 waves). Contains syncthreads.
static __device__ __forceinline__ unsigned blockScanExcl(unsigned v, unsigned t,
                                                         unsigned* lw, unsigned* tot){
  unsigned lane = t & 63u, w = t >> 6;
  unsigned x = v;
  #pragma unroll
  for (int off = 1; off < 64; off <<= 1){
    unsigned y = __shfl_up(x, off, 64);
    if (lane >= (unsigned)off) x += y;
  }
  if (lane == 63u) lw[w] = x;
  __syncthreads();
  unsigned woff = 0;
  for (unsigned i = 0; i < w; i++) woff += lw[i];
  *tot = lw[0] + lw[1] + lw[2] + lw[3];
  __syncthreads();
  return x + woff - v;
}

// Build packed contributions (high32 = key, low32 = value bits) with fused
// per-tile pass-1 (low key byte) histogram. NO cross-block sync (round-6
// lesson: agent-scope signal/spin costs >> a kernel boundary).
__global__ __launch_bounds__(256) void k_build_h(const int* __restrict__ sidx,
    const int* __restrict__ ridx, const float* __restrict__ rval,
    const float* __restrict__ grad, uint64_t* __restrict__ A,
    unsigned* __restrict__ gh){
  __shared__ unsigned h[256];
  unsigned t = threadIdx.x;
  h[t] = 0; __syncthreads();
  unsigned base = blockIdx.x * (unsigned)TILE;
  #pragma unroll
  for (int r = 0; r < 16; r++){
    unsigned i = base + (unsigned)r*256u + t;
    uint32_t key, vb;
    if (i < S_N){
      key = (uint32_t)sidx[i];
      vb  = __float_as_uint(fabsf(grad[i]));
    } else if (i < N1){
      unsigned j = i - S_N;
      key = (uint32_t)(ridx[2u*j] * CDIM + ridx[2u*j + 1u]);
      const float ADJF = (float)(1.0 - (3355443.0 / 16777216.0) * (1.0 - 0.95));
      vb = __float_as_uint(ADJF * rval[j]);
    } else { key = PAD_KEY; vb = PAD_VAL; }
    A[i] = ((uint64_t)key << 32) | (uint64_t)vb;
    atomicAdd(&h[key & 0xFFu], 1u);
  }
  __syncthreads();
  gh[t*NTILES + blockIdx.x] = h[t];
}

// Per-tile 256-bin histogram of digit (e >> shift) & 0xFF. Layout [digit][tile].
__global__ __launch_bounds__(256) void k_hist(const uint64_t* __restrict__ in, unsigned shift,
                                              unsigned* __restrict__ gh, unsigned nt){
  __shared__ unsigned h[256];
  unsigned t = threadIdx.x;
  h[t] = 0; __syncthreads();
  size_t base = (size_t)blockIdx.x * TILE;
  #pragma unroll
  for (int r = 0; r < 16; r++){
    uint64_t e = in[base + (size_t)r*256 + t];
    atomicAdd(&h[(unsigned)((e >> shift) & 0xFF)], 1u);
  }
  __syncthreads();
  gh[t * nt + blockIdx.x] = h[t];
}

// Row scan: block d turns gh[d][*] into exclusive tile prefixes + digit total.
__global__ __launch_bounds__(256) void k_scanrows(unsigned* __restrict__ gh,
                                                  unsigned* __restrict__ dtot, unsigned nt){
  __shared__ unsigned lw[4];
  unsigned d = blockIdx.x, t = threadIdx.x;
  unsigned carry = 0;
  for (unsigned base = 0; base < nt; base += 256){
    unsigned i = base + t;
    unsigned v = (i < nt) ? gh[d * nt + i] : 0u;
    unsigned tot;
    unsigned e = blockScanExcl(v, t, lw, &tot);
    if (i < nt) gh[d * nt + i] = e + carry;
    carry += tot;
  }
  if (t == 0) dtot[d] = carry;
}

// ---- LDS-staged stable radix scatter (round-2 proven) --------------------
template <bool FINAL>
__device__ __forceinline__ void scatter_body(const uint64_t* __restrict__ in,
                                             uint64_t* __restrict__ out,
                                             float* __restrict__ fout,
                                             unsigned shift,
                                             const unsigned* __restrict__ gh,
                                             const unsigned* __restrict__ dtot,
                                             unsigned nt){
  __shared__ unsigned wrun[4*256];
  __shared__ unsigned gput[256];
  __shared__ unsigned lw[4];
  __shared__ uint64_t stage[TILE];       // 32 KB
  unsigned t = threadIdx.x, lane = t & 63u, w = t >> 6;
  wrun[t] = 0; wrun[256+t] = 0; wrun[512+t] = 0; wrun[768+t] = 0;
  __syncthreads();
  uint64_t ltm = (lane == 0) ? 0ull : (~0ull >> (64u - lane));
  uint64_t elems[16]; unsigned rnk[16]; unsigned dg[16];
  size_t base = (size_t)blockIdx.x * TILE + (size_t)w * 1024;
  #pragma unroll
  for (int r = 0; r < 16; r++){
    uint64_t e = in[base + (size_t)r*64 + lane];
    elems[r] = e;
    unsigned d = (unsigned)((e >> shift) & 0xFF);
    uint64_t m = ~0ull;
    #pragma unroll
    for (int b = 0; b < 8; b++){
      uint64_t bb = __ballot((d >> b) & 1u);
      m &= ((d >> b) & 1u) ? bb : ~bb;
    }
    unsigned rr   = (unsigned)__popcll(m & ltm);
    unsigned prev = wrun[w*256 + d];
    __builtin_amdgcn_wave_barrier();
    if (rr == 0) wrun[w*256 + d] = prev + (unsigned)__popcll(m);
    __builtin_amdgcn_wave_barrier();
    rnk[r] = prev + rr;
    dg[r]  = d;
  }
  __syncthreads();
  {
    unsigned d = t;
    unsigned c0 = wrun[d], c1 = wrun[256+d], c2 = wrun[512+d], c3 = wrun[768+d];
    unsigned cnt = c0 + c1 + c2 + c3;
    unsigned tot, tot2;
    unsigned ldig  = blockScanExcl(cnt, t, lw, &tot);
    unsigned dbase = blockScanExcl(dtot[d], t, lw, &tot2);
    gput[d] = dbase + gh[d * nt + blockIdx.x] - ldig;
    wrun[d]       = ldig;
    wrun[256 + d] = ldig + c0;
    wrun[512 + d] = ldig + c0 + c1;
    wrun[768 + d] = ldig + c0 + c1 + c2;
  }
  __syncthreads();
  #pragma unroll
  for (int r = 0; r < 16; r++)
    stage[ wrun[w*256 + dg[r]] + rnk[r] ] = elems[r];
  __syncthreads();
  #pragma unroll
  for (int r = 0; r < 16; r++){
    unsigned j = (unsigned)r * 256u + t;
    uint64_t e = stage[j];
    unsigned d = (unsigned)((e >> shift) & 0xFF);
    unsigned dest = gput[d] + j;
    if (FINAL){
      if (dest < R_N){
        uint32_t key = (uint32_t)(e >> 32);
        fout[2u*dest]        = (float)(key >> 12);
        fout[2u*dest + 1u]   = (float)(key & 4095u);
        fout[2u*R_N + dest]  = __uint_as_float(~(uint32_t)e);
      }
    } else {
      out[dest] = e;
    }
  }
}

__global__ __launch_bounds__(256) void k_scatter(const uint64_t* __restrict__ in,
    uint64_t* __restrict__ out, unsigned shift, const unsigned* __restrict__ gh,
    const unsigned* __restrict__ dtot, unsigned nt){
  scatter_body<false>(in, out, nullptr, shift, gh, dtot, nt);
}
__global__ __launch_bounds__(256) void k_scatter_out(const uint64_t* __restrict__ in,
    float* __restrict__ fout, unsigned shift, const unsigned* __restrict__ gh,
    const unsigned* __restrict__ dtot, unsigned nt){
  scatter_body<true>(in, nullptr, fout, shift, gh, dtot, nt);
}

// In-order segmented sum, SPARSE output (candidate at head position, PADREC
// elsewhere -> survivors stay key-ascending; no headcount/scan/prefill).
// Fused: per-tile 12-bit sortkey-prefix histogram (u16 row) for radix-select.
// fp32 walk in original contribution order == segment_sum bit-exact.
__global__ __launch_bounds__(256) void k_segsum12(const uint64_t* __restrict__ in,
    uint64_t* __restrict__ out, unsigned short* __restrict__ g12){
  __shared__ unsigned h12[4096];         // 16 KB
  unsigned t = threadIdx.x;
  for (unsigned j = t; j < 4096u; j += 256u) h12[j] = 0;
  __syncthreads();
  size_t base = (size_t)blockIdx.x * TILE;
  for (int r = 0; r < 16; r++){
    size_t p = base + (size_t)r*256 + t;
    uint64_t e0 = in[p];
    uint32_t k = (uint32_t)(e0 >> 32);
    uint32_t vb0 = (uint32_t)e0;
    bool head = ((p == 0) || ((uint32_t)(in[p-1] >> 32) != k)) && (vb0 != PAD_VAL);
    uint64_t rec = PADREC;
    if (head){
      float s = __uint_as_float(vb0);
      size_t q = p + 1;
      while (q < NPAD){
        uint64_t e = in[q];
        if ((uint32_t)(e >> 32) != k) break;
        uint32_t vb = (uint32_t)e;
        if (vb == PAD_VAL) break;
        s += __uint_as_float(vb);
        q++;
      }
      uint32_t sk = ~__float_as_uint(s);
      rec = ((uint64_t)k << 32) | (uint64_t)sk;
      atomicAdd(&h12[sk >> 20], 1u);
    }
    out[p] = rec;
  }
  __syncthreads();
  unsigned short* row = g12 + (size_t)blockIdx.x * 4096;
  for (unsigned j = t; j < 4096u; j += 256u) row[j] = (unsigned short)h12[j];
}

// Fold g12 rows: block b sums tiles [68b, 68b+68) -> partial[b][4096].
__global__ __launch_bounds__(256) void k_fold12(const unsigned short* __restrict__ g12,
    unsigned* __restrict__ partial){
  __shared__ unsigned acc[4096];
  unsigned t = threadIdx.x;
  for (unsigned j = t; j < 4096u; j += 256u) acc[j] = 0;
  __syncthreads();
  unsigned t0 = blockIdx.x * 68u, t1 = min(t0 + 68u, (unsigned)NTILES);
  for (unsigned tile = t0; tile < t1; tile++){
    const unsigned short* row = g12 + (size_t)tile * 4096;
    for (unsigned j = t; j < 4096u; j += 256u) acc[j] += row[j];
  }
  __syncthreads();
  for (unsigned j = t; j < 4096u; j += 256u) partial[blockIdx.x*4096u + j] = acc[j];
}

// Pick thr12: first 12-bit bin where cumulative >= R. Single block.
__global__ __launch_bounds__(256) void k_pick12(const unsigned* __restrict__ partial,
    unsigned* __restrict__ sel){
  __shared__ unsigned acc[4096];
  __shared__ unsigned lw[4];
  __shared__ unsigned fl[4];
  __shared__ unsigned thr_sh;
  unsigned t = threadIdx.x, lane = t & 63u, w = t >> 6;
  for (unsigned j = t; j < 4096u; j += 256u){
    unsigned s = 0;
    for (unsigned i = 0; i < 16u; i++) s += partial[i*4096u + j];
    acc[j] = s;
  }
  if (t == 0) thr_sh = 0xFFFFFFFFu;
  __syncthreads();
  unsigned carry = 0;
  for (unsigned c = 0; c < 16u; c++){
    unsigned v = acc[c*256u + t];
    unsigned tot; unsigned e = blockScanExcl(v, t, lw, &tot);
    bool f = (carry + e + v >= (unsigned)R_N);
    uint64_t m = __ballot(f);
    if (lane == 0)
      fl[w] = m ? (w*64u + (unsigned)__ffsll((unsigned long long)m) - 1u) : 0xFFFFFFFFu;
    __syncthreads();
    if (t == 0 && thr_sh == 0xFFFFFFFFu){
      unsigned bb = min(min(fl[0], fl[1]), min(fl[2], fl[3]));
      if (bb != 0xFFFFFFFFu) thr_sh = c*256u + bb;
    }
    __syncthreads();
    carry += tot;
  }
  if (t == 0) sel[0] = (thr_sh == 0xFFFFFFFFu) ? 4095u : thr_sh;
}

// Per-tile survivor count from g12 (no re-read of A).
__global__ __launch_bounds__(256) void k_tilecnt(const unsigned short* __restrict__ g12,
    const unsigned* __restrict__ sel, unsigned* __restrict__ ccnt){
  __shared__ unsigned lw[4];
  __shared__ unsigned thr_sh;
  unsigned t = threadIdx.x;
  if (t == 0) thr_sh = sel[0];
  __syncthreads();
  unsigned thr = thr_sh;
  const unsigned short* row = g12 + (size_t)blockIdx.x * 4096;
  unsigned s = 0;
  for (unsigned j = t; j <= thr; j += 256u) s += row[j];
  unsigned tot; blockScanExcl(s, t, lw, &tot);
  if (t == 0) ccnt[blockIdx.x] = tot;
}

// Single-block exclusive scan of the 1076 tile counts (in place) + mtot.
__global__ __launch_bounds__(256) void k_scanbases(unsigned* __restrict__ ccnt,
                                                   unsigned* __restrict__ mtot){
  __shared__ unsigned buf[NTILES];       // 4.3 KB
  __shared__ unsigned lw[4];
  unsigned t = threadIdx.x;
  for (unsigned i = t; i < NTILES; i += 256u) buf[i] = ccnt[i];
  __syncthreads();
  unsigned carry = 0;
  for (unsigned base = 0; base < NTILES; base += 256u){
    unsigned i = base + t;
    unsigned v = (i < NTILES) ? buf[i] : 0u;
    unsigned tt; unsigned e = blockScanExcl(v, t, lw, &tt);
    if (i < NTILES) ccnt[i] = carry + e;
    carry += tt;
  }
  if (t == 0) mtot[0] = carry;
}

// Stable per-tile compaction of survivors (sk12 <= thr) A0 -> A1[0,M),
// fused PADREC tail fill of [M, SPAD). (Round-6 proven.)
__global__ __launch_bounds__(256) void k_compact(const uint64_t* __restrict__ A0,
    uint64_t* __restrict__ A1, const unsigned* __restrict__ cbase,
    const unsigned* __restrict__ mtot, const unsigned* __restrict__ sel){
  __shared__ unsigned wsum[4];
  __shared__ unsigned thr_sh;
  unsigned t = threadIdx.x, lane = t & 63u, w = t >> 6;
  if (t == 0) thr_sh = sel[0];
  __syncthreads();
  unsigned thr = thr_sh;
  uint64_t ltm = (lane == 0) ? 0ull : (~0ull >> (64u - lane));
  uint64_t e[16]; unsigned rnk[16]; unsigned qb = 0;
  size_t base = (size_t)blockIdx.x * TILE + (size_t)w * 1024;
  unsigned wcount = 0;
  #pragma unroll
  for (int r = 0; r < 16; r++){
    uint64_t x = A0[base + (size_t)r*64 + lane];
    e[r] = x;
    bool q = ((((uint32_t)x) >> 20) <= thr);
    uint64_t m = __ballot(q);
    rnk[r] = wcount + (unsigned)__popcll(m & ltm);
    wcount += (unsigned)__popcll(m);
    qb |= (q ? 1u : 0u) << r;
  }
  if (lane == 0) wsum[w] = wcount;
  __syncthreads();
  unsigned woff = 0;
  for (unsigned i = 0; i < w; i++) woff += wsum[i];
  unsigned b0 = cbase[blockIdx.x] + woff;
  #pragma unroll
  for (int r = 0; r < 16; r++)
    if ((qb >> r) & 1u){
      unsigned dest = b0 + rnk[r];
      if (dest < (unsigned)SPAD) A1[dest] = e[r];
    }
  unsigned M = mtot[0];
  for (size_t p = (size_t)M + blockIdx.x*256u + t; p < (size_t)SPAD; p += (size_t)NTILES*256u)
    A1[p] = PADREC;
}

extern "C" void kernel_launch(void* const* d_in, const int* in_sizes, int n_in,
                              void* d_out, int out_size, void* d_ws, size_t ws_size,
                              hipStream_t stream) {
  const int*   sidx = (const int*)d_in[0];
  const int*   ridx = (const int*)d_in[1];
  const float* rval = (const float*)d_in[2];
  const float* grad = (const float*)d_in[3];
  float* out = (float*)d_out;

  uint64_t* A0      = (uint64_t*)d_ws;                    // 35.3 MB
  uint64_t* A1      = A0 + NPAD;                          // 35.3 MB
  unsigned* gh      = (unsigned*)(A1 + NPAD);             // 1.1 MB
  unsigned* dtot    = gh + 256 * NTILES;                  // 1 KB
  unsigned* partial = dtot + 256;                         // 256 KB
  unsigned* ccnt    = partial + 16*4096;                  // 4.3 KB
  unsigned* mtot    = ccnt + NTILES;                      // 4 B
  unsigned* sel     = mtot + 1;                           // 16 B
  unsigned short* g12 = (unsigned short*)(sel + 4);       // 8.8 MB

  // Build (+fused pass-1 hist); stable key sort 3 x 8-bit. A0->A1->A0->A1.
  k_build_h <<<NTILES, 256, 0, stream>>>(sidx, ridx, rval, grad, A0, gh);
  k_scanrows<<<256,    256, 0, stream>>>(gh, dtot, NTILES);
  k_scatter <<<NTILES, 256, 0, stream>>>(A0, A1, 32, gh, dtot, NTILES);
  k_hist    <<<NTILES, 256, 0, stream>>>(A1, 40, gh, NTILES);
  k_scanrows<<<256,    256, 0, stream>>>(gh, dtot, NTILES);
  k_scatter <<<NTILES, 256, 0, stream>>>(A1, A0, 40, gh, dtot, NTILES);
  k_hist    <<<NTILES, 256, 0, stream>>>(A0, 48, gh, NTILES);
  k_scanrows<<<256,    256, 0, stream>>>(gh, dtot, NTILES);
  k_scatter <<<NTILES, 256, 0, stream>>>(A0, A1, 48, gh, dtot, NTILES);

  // Coalesce sparse (A1 -> A0) + per-tile 12-bit select hist; pick threshold;
  // survivor counts/bases from g12; stable compact + tail fill (A0 -> A1).
  k_segsum12 <<<NTILES, 256, 0, stream>>>(A1, A0, g12);
  k_fold12   <<<16,     256, 0, stream>>>(g12, partial);
  k_pick12   <<<1,      256, 0, stream>>>(partial, sel);
  k_tilecnt  <<<NTILES, 256, 0, stream>>>(g12, sel, ccnt);
  k_scanbases<<<1,      256, 0, stream>>>(ccnt, mtot);
  k_compact  <<<NTILES, 256, 0, stream>>>(A0, A1, ccnt, mtot, sel);

  // Stable value sort on survivors: 4 x 8-bit, final fused with output.
  // A1->A0->A1->A0->out.
  k_hist    <<<NT2, 256, 0, stream>>>(A1, 0, gh, NT2);
  k_scanrows<<<256, 256, 0, stream>>>(gh, dtot, NT2);
  k_scatter <<<NT2, 256, 0, stream>>>(A1, A0, 0, gh, dtot, NT2);
  k_hist    <<<NT2, 256, 0, stream>>>(A0, 8, gh, NT2);
  k_scanrows<<<256, 256, 0, stream>>>(gh, dtot, NT2);
  k_scatter <<<NT2, 256, 0, stream>>>(A0, A1, 8, gh, dtot, NT2);
  k_hist    <<<NT2, 256, 0, stream>>>(A1, 16, gh, NT2);
  k_scanrows<<<256, 256, 0, stream>>>(gh, dtot, NT2);
  k_scatter <<<NT2, 256, 0, stream>>>(A1, A0, 16, gh, dtot, NT2);
  k_hist       <<<NT2, 256, 0, stream>>>(A0, 24, gh, NT2);
  k_scanrows   <<<256, 256, 0, stream>>>(gh, dtot, NT2);
  k_scatter_out<<<NT2, 256, 0, stream>>>(A0, out, 24, gh, dtot, NT2);
}